// Round 5
// baseline (128.335 us; speedup 1.0000x reference)
//
#include <hip/hip_runtime.h>
#include <hip/hip_cooperative_groups.h>

namespace cg = cooperative_groups;

// B=16, C=3, H=256, W=256 fp32. 48 slices of 256x256.
// out = inverted, per-slice max-normalized, per-channel-weighted exact EDT.
//
// Pipeline (2 launches; d2 never touches memory):
//   K1: wave per row -> four 64-bit zero-ballots per row (32 B/row) into d_ws.
//   K2 (cooperative, 768 blocks = 3/CU): per 16-col strip:
//       slice bitmask (8 KB) -> LDS; g^2 in-LDS via clz/ctz nearest-zero;
//       +-16 windowed min-plus (exact when result <= 288, per-pixel full-column
//       fallback otherwise -> unconditionally exact); strip max -> d_ws;
//       grid.sync(); slice max = max of 16 strip maxes; epilogue
//       out = (mx - w*sqrt(d2))/mx applied straight from registers.

#define PADV 1e30f

// ---------------- K1: row bitmask via ballots -------------------------------
// One wave per row. Lane l holds cols 4l..4l+3; b_cc bit l = (col 4l+cc == 0).
__global__ __launch_bounds__(256) void k1_bitmask(const float* __restrict__ in,
                                                  unsigned long long* __restrict__ bits) {
    int row = blockIdx.x * 4 + (threadIdx.x >> 6);
    int lane = threadIdx.x & 63;
    const float4 m = ((const float4*)in)[(long)row * 64 + lane];

    unsigned long long b0 = __ballot(m.x == 0.f);
    unsigned long long b1 = __ballot(m.y == 0.f);
    unsigned long long b2 = __ballot(m.z == 0.f);
    unsigned long long b3 = __ballot(m.w == 0.f);
    if (lane == 0) {
        ulonglong4* dst = (ulonglong4*)(bits + (long)row * 4);
        ulonglong4 v; v.x = b0; v.y = b1; v.z = b2; v.w = b3;
        *dst = v;
    }
}

// ---------------- K2: fused exact min-plus + epilogue (cooperative) ---------
// Block = 256 threads = one slice's 16-col strip (grid 48*16 = 768 = 3/CU).
__global__ __launch_bounds__(256, 3) void k2_fused(const unsigned long long* __restrict__ bits,
                                                   float* __restrict__ out,
                                                   float* __restrict__ stripmax) {
    __shared__ unsigned long long bm[1024];   // [row*4 + cc]
    __shared__ float tile[16 * 289];
    __shared__ float wm[4];
    __shared__ float sMx;
    cg::grid_group grid = cg::this_grid();

    int bx = blockIdx.x;
    int slice = bx >> 4;
    int w0 = (bx & 15) * 16;
    int tid = threadIdx.x;

    // load slice bitmask: 1024 ull, coalesced
    {
        const unsigned long long* src = bits + (long)slice * 1024;
        #pragma unroll
        for (int i = 0; i < 4; ++i) bm[i * 256 + tid] = src[i * 256 + tid];
    }
    // pad rows of the tile
    {
        int c = tid >> 4, i = tid & 15;
        tile[c * 289 + i] = PADV;
        tile[c * 289 + 272 + i] = PADV;
    }
    __syncthreads();

    int c = tid & 15;                 // column within strip
    int p = w0 + c;                   // global column 0..255
    int rg = tid >> 4;                // 0..15

    // nearest-zero squared distance for (row, col p) from LDS bitmask
    auto nz2 = [&](int row) -> float {
        int dist = 512;               // BIG cap (H+W), matches reference
        #pragma unroll
        for (int cc = 0; cc < 4; ++cc) {
            unsigned long long M = bm[row * 4 + cc];
            int q = p - cc;                          // >= -3
            int qa = (q < 0) ? 0 : q;
            int tp = qa >> 2;                        // floor(q/4) for q>=0
            unsigned long long Ml = (q >= 0) ? (M & (~0ull >> (63 - tp))) : 0ull;
            int tn = (q < 0) ? 0 : ((q + 3) >> 2);   // ceil(q/4)
            unsigned long long Mh = (tn < 64) ? (M & (~0ull << tn)) : 0ull;
            if (Ml) dist = min(dist, q - 4 * (63 - __builtin_clzll(Ml)));
            if (Mh) dist = min(dist, 4 * __builtin_ctzll(Mh) - q);
        }
        float fd = (float)dist;
        return fd * fd;
    };

    // g2 for 16 rows each (strided rows -> <=2-way LDS write alias, free)
    #pragma unroll
    for (int k = 0; k < 16; ++k) {
        int r = rg + 16 * k;
        tile[c * 289 + 16 + r] = nz2(r);
    }
    __syncthreads();

    // window pass: contiguous ownership rows r0..r0+15
    int r0 = rg * 16;
    float s[48];                       // rows r0-16 .. r0+31 of column c
    #pragma unroll
    for (int i = 0; i < 48; ++i) s[i] = tile[c * 289 + r0 + i];

    float dmin[16];
    #pragma unroll
    for (int k = 0; k < 16; ++k) dmin[k] = s[k + 16];   // o = 0
    #pragma unroll
    for (int o = -16; o <= 16; ++o) {
        if (o == 0) continue;
        float oo = (float)(o * o);
        #pragma unroll
        for (int k = 0; k < 16; ++k)
            dmin[k] = fminf(dmin[k], s[k + 16 + o] + oo);
    }

    // per-pixel exact fallback (window can't certify when min > 288; column is
    // in LDS). Never taken for random masks -> execz-skipped.
    #pragma unroll
    for (int k = 0; k < 16; ++k) {
        if (dmin[k] > 288.0f) {
            float best = dmin[k];
            int r = r0 + k;
            for (int rp = 0; rp < 256; ++rp) {
                float dr = (float)(r - rp);
                best = fminf(best, fmaf(dr, dr, tile[c * 289 + 16 + rp]));
            }
            dmin[k] = best;
        }
    }

    // block (strip) max -> plain store, no init required
    float m = 0.f;
    #pragma unroll
    for (int k = 0; k < 16; ++k) m = fmaxf(m, dmin[k]);
    #pragma unroll
    for (int off = 32; off >= 1; off >>= 1)
        m = fmaxf(m, __shfl_down(m, off, 64));
    if ((tid & 63) == 0) wm[tid >> 6] = m;
    __syncthreads();
    if (tid == 0)
        stripmax[bx] = fmaxf(fmaxf(wm[0], wm[1]), fmaxf(wm[2], wm[3]));

    // ---- all strips done -> slice max is complete ----
    grid.sync();

    if (tid < 16) {
        float v = stripmax[slice * 16 + tid];
        #pragma unroll
        for (int off = 8; off >= 1; off >>= 1) v = fmaxf(v, __shfl_down(v, off, 64));
        if (tid == 0) sMx = v;
    }
    __syncthreads();

    int ch = slice % 3;
    float wgt = (ch == 0) ? 0.5f : ((ch == 1) ? 1.0f : 2.0f);
    float mx = wgt * __builtin_sqrtf(sMx);

    float* dst = out + (long)slice * 65536 + w0 + c;
    if (mx > 0.f) {
        float inv = 1.0f / mx;
        #pragma unroll
        for (int k = 0; k < 16; ++k)
            dst[(long)(r0 + k) * 256] = (mx - wgt * __builtin_sqrtf(dmin[k])) * inv;
    } else {
        #pragma unroll
        for (int k = 0; k < 16; ++k)
            dst[(long)(r0 + k) * 256] = wgt * __builtin_sqrtf(dmin[k]);
    }
}

extern "C" void kernel_launch(void* const* d_in, const int* in_sizes, int n_in,
                              void* d_out, int out_size, void* d_ws, size_t ws_size,
                              hipStream_t stream) {
    const float* in = (const float*)d_in[0];
    float* out = (float*)d_out;
    float* stripmax = (float*)d_ws;                                        // 768 floats
    unsigned long long* bits = (unsigned long long*)((char*)d_ws + 4096);  // 384 KB

    k1_bitmask<<<3072, 256, 0, stream>>>(in, bits);       // 12288 rows, wave/row

    void* args[] = { (void*)&bits, (void*)&out, (void*)&stripmax };
    hipLaunchCooperativeKernel((const void*)k2_fused, dim3(768), dim3(256),
                               args, 0, stream);
}

// Round 6
// 93.041 us; speedup vs baseline: 1.3793x; 1.3793x over previous
//
#include <hip/hip_runtime.h>

// B=16, C=3, H=256, W=256 fp32. 48 slices of 256x256.
// out = inverted, per-slice max-normalized, per-channel-weighted exact EDT.
//
// Pipeline (3 launches, no atomics, no grid sync, d2 never touches HBM):
//   K1: wave per row -> four 64-bit zero-ballots per row (32 B/row) into d_ws.
//   K2: per 16-col strip: slice bitmask (8 KB) -> LDS; g^2 in-LDS via clz/ctz;
//       +-16 windowed min-plus (exact when <= 288; per-pixel full-column
//       fallback otherwise -> unconditionally exact); writes ONLY the strip
//       max (plain store).
//   K3: recomputes the identical window pass from the bitmask (cheap VALU),
//       reduces 16 strip maxes -> slice max, applies epilogue
//       out = (mx - w*sqrt(d2))/mx straight from registers. Only writer of out.
//
// NOTE (R5 post-mortem): cooperative grid.sync() across 768 blocks cost ~45 us
// on gfx950 (cross-XCD barrier) — never fuse through a grid barrier here.

#define PADV 1e30f

// ---------------- K1: row bitmask via ballots -------------------------------
__global__ __launch_bounds__(256) void k1_bitmask(const float* __restrict__ in,
                                                  unsigned long long* __restrict__ bits) {
    int row = blockIdx.x * 4 + (threadIdx.x >> 6);
    int lane = threadIdx.x & 63;
    const float4 m = ((const float4*)in)[(long)row * 64 + lane];

    unsigned long long b0 = __ballot(m.x == 0.f);
    unsigned long long b1 = __ballot(m.y == 0.f);
    unsigned long long b2 = __ballot(m.z == 0.f);
    unsigned long long b3 = __ballot(m.w == 0.f);
    if (lane == 0) {
        ulonglong4* dst = (ulonglong4*)(bits + (long)row * 4);
        ulonglong4 v; v.x = b0; v.y = b1; v.z = b2; v.w = b3;
        *dst = v;
    }
}

// ---------------- shared worker: exact per-thread dmin[16] ------------------
// Block = 256 threads = one slice's 16-col strip. Loads slice bitmask into
// bm[1024], builds the g2 tile in LDS (stride 289, 16 pad rows each side),
// runs the +-16 window with per-pixel exact fallback. On return, dmin[k] is
// the exact d2 for (row r0+k, col w0+c) and the caller's (c, r0) are set.
__device__ __forceinline__ void strip_dmin(const unsigned long long* __restrict__ bits,
                                           unsigned long long* bm, float* tile,
                                           int slice, int w0, int tid,
                                           float dmin[16], int& c_out, int& r0_out) {
    // load slice bitmask: 1024 ull, coalesced
    {
        const unsigned long long* src = bits + (long)slice * 1024;
        #pragma unroll
        for (int i = 0; i < 4; ++i) bm[i * 256 + tid] = src[i * 256 + tid];
    }
    // pad rows of the tile
    {
        int c = tid >> 4, i = tid & 15;
        tile[c * 289 + i] = PADV;
        tile[c * 289 + 272 + i] = PADV;
    }
    __syncthreads();

    int c = tid & 15;                 // column within strip
    int p = w0 + c;                   // global column 0..255
    int rg = tid >> 4;                // 0..15

    auto nz2 = [&](int row) -> float {
        int dist = 512;               // BIG cap (H+W), matches reference
        #pragma unroll
        for (int cc = 0; cc < 4; ++cc) {
            unsigned long long M = bm[row * 4 + cc];
            int q = p - cc;                          // >= -3
            int qa = (q < 0) ? 0 : q;
            int tp = qa >> 2;                        // floor(q/4) for q>=0
            unsigned long long Ml = (q >= 0) ? (M & (~0ull >> (63 - tp))) : 0ull;
            int tn = (q < 0) ? 0 : ((q + 3) >> 2);   // ceil(q/4)
            unsigned long long Mh = (tn < 64) ? (M & (~0ull << tn)) : 0ull;
            if (Ml) dist = min(dist, q - 4 * (63 - __builtin_clzll(Ml)));
            if (Mh) dist = min(dist, 4 * __builtin_ctzll(Mh) - q);
        }
        float fd = (float)dist;
        return fd * fd;
    };

    // g2 for 16 rows each (strided rows -> <=2-way LDS write alias, free)
    #pragma unroll
    for (int k = 0; k < 16; ++k) {
        int r = rg + 16 * k;
        tile[c * 289 + 16 + r] = nz2(r);
    }
    __syncthreads();

    // window pass: contiguous ownership rows r0..r0+15
    int r0 = rg * 16;
    float s[48];
    #pragma unroll
    for (int i = 0; i < 48; ++i) s[i] = tile[c * 289 + r0 + i];

    #pragma unroll
    for (int k = 0; k < 16; ++k) dmin[k] = s[k + 16];   // o = 0
    #pragma unroll
    for (int o = -16; o <= 16; ++o) {
        if (o == 0) continue;
        float oo = (float)(o * o);
        #pragma unroll
        for (int k = 0; k < 16; ++k)
            dmin[k] = fminf(dmin[k], s[k + 16 + o] + oo);
    }

    // per-pixel exact fallback (never taken for random masks -> execz-skipped)
    #pragma unroll
    for (int k = 0; k < 16; ++k) {
        if (dmin[k] > 288.0f) {
            float best = dmin[k];
            int r = r0 + k;
            for (int rp = 0; rp < 256; ++rp) {
                float dr = (float)(r - rp);
                best = fminf(best, fmaf(dr, dr, tile[c * 289 + 16 + rp]));
            }
            dmin[k] = best;
        }
    }
    c_out = c; r0_out = r0;
}

// ---------------- K2: strip max only ---------------------------------------
__global__ __launch_bounds__(256) void k2_stripmax(const unsigned long long* __restrict__ bits,
                                                   float* __restrict__ stripmax) {
    __shared__ unsigned long long bm[1024];
    __shared__ float tile[16 * 289];
    __shared__ float wm[4];
    int bx = blockIdx.x;
    int tid = threadIdx.x;

    float dmin[16]; int c, r0;
    strip_dmin(bits, bm, tile, bx >> 4, (bx & 15) * 16, tid, dmin, c, r0);

    float m = 0.f;
    #pragma unroll
    for (int k = 0; k < 16; ++k) m = fmaxf(m, dmin[k]);
    #pragma unroll
    for (int off = 32; off >= 1; off >>= 1)
        m = fmaxf(m, __shfl_down(m, off, 64));
    if ((tid & 63) == 0) wm[tid >> 6] = m;
    __syncthreads();
    if (tid == 0)
        stripmax[bx] = fmaxf(fmaxf(wm[0], wm[1]), fmaxf(wm[2], wm[3]));
}

// ---------------- K3: recompute + epilogue ---------------------------------
__global__ __launch_bounds__(256) void k3_final(const unsigned long long* __restrict__ bits,
                                                const float* __restrict__ stripmax,
                                                float* __restrict__ out) {
    __shared__ unsigned long long bm[1024];
    __shared__ float tile[16 * 289];
    __shared__ float sMx;
    int bx = blockIdx.x;
    int slice = bx >> 4;
    int w0 = (bx & 15) * 16;
    int tid = threadIdx.x;

    // slice max from the 16 strip maxes (issue early, independent of tile work)
    if (tid < 16) {
        float v = stripmax[slice * 16 + tid];
        #pragma unroll
        for (int off = 8; off >= 1; off >>= 1) v = fmaxf(v, __shfl_down(v, off, 64));
        if (tid == 0) sMx = v;
    }

    float dmin[16]; int c, r0;
    strip_dmin(bits, bm, tile, slice, w0, tid, dmin, c, r0);
    __syncthreads();                  // sMx visible (also ordered by strip_dmin's syncs)

    int ch = slice % 3;
    float wgt = (ch == 0) ? 0.5f : ((ch == 1) ? 1.0f : 2.0f);
    float mx = wgt * __builtin_sqrtf(sMx);

    float* dst = out + (long)slice * 65536 + w0 + c;
    if (mx > 0.f) {
        float inv = 1.0f / mx;
        #pragma unroll
        for (int k = 0; k < 16; ++k)
            dst[(long)(r0 + k) * 256] = (mx - wgt * __builtin_sqrtf(dmin[k])) * inv;
    } else {
        #pragma unroll
        for (int k = 0; k < 16; ++k)
            dst[(long)(r0 + k) * 256] = wgt * __builtin_sqrtf(dmin[k]);
    }
}

extern "C" void kernel_launch(void* const* d_in, const int* in_sizes, int n_in,
                              void* d_out, int out_size, void* d_ws, size_t ws_size,
                              hipStream_t stream) {
    const float* in = (const float*)d_in[0];
    float* out = (float*)d_out;
    float* stripmax = (float*)d_ws;                                        // 768 floats
    unsigned long long* bits = (unsigned long long*)((char*)d_ws + 4096);  // 384 KB

    k1_bitmask<<<3072, 256, 0, stream>>>(in, bits);          // 12288 rows, wave/row
    k2_stripmax<<<768, 256, 0, stream>>>(bits, stripmax);    // strip maxes only
    k3_final<<<768, 256, 0, stream>>>(bits, stripmax, out);  // recompute + epilogue
}

// Round 7
// 83.138 us; speedup vs baseline: 1.5436x; 1.1191x over previous
//
#include <hip/hip_runtime.h>

// B=16, C=3, H=256, W=256 fp32. 48 slices of 256x256.
// out = inverted, per-slice max-normalized, per-channel-weighted exact EDT.
//
// Pipeline (3 launches — R4 structure, the measured best):
//   K1: wave per row -> four 64-bit zero-ballots per row (32 B/row) into d_ws.
//   K2: per 16-col strip: slice bitmask (8 KB) -> LDS; g^2 in-LDS via clz/ctz;
//       +-8 windowed min-plus (windowed min <= 80 certifies exactness: any
//       |o|>=9 candidate >= 81; per-pixel full-column fallback otherwise ->
//       unconditionally exact). Writes d2 (L2-resident round trip) + strip max.
//   K3: reads d2 (L2-hot) + 16 strip maxes -> slice max; epilogue
//       out = (mx - w*sqrt(d2))/mx.
//
// Post-mortem notes:
//   R5: cooperative grid.sync() over 768 blocks costs ~45 us (cross-XCD) — never.
//   R6: recomputing the VALU-heavy pass to skip the d2 round trip lost 5+ us;
//       the 12.6 MB d2 intermediate lives in L2 and is nearly free.

#define PADV 1e30f

// ---------------- K1: row bitmask via ballots -------------------------------
// One wave per row. Lane l holds cols 4l..4l+3; b_cc bit l = (col 4l+cc == 0).
__global__ __launch_bounds__(256) void k1_bitmask(const float* __restrict__ in,
                                                  unsigned long long* __restrict__ bits) {
    int row = blockIdx.x * 4 + (threadIdx.x >> 6);
    int lane = threadIdx.x & 63;
    const float4 m = ((const float4*)in)[(long)row * 64 + lane];

    unsigned long long b0 = __ballot(m.x == 0.f);
    unsigned long long b1 = __ballot(m.y == 0.f);
    unsigned long long b2 = __ballot(m.z == 0.f);
    unsigned long long b3 = __ballot(m.w == 0.f);
    if (lane == 0) {
        ulonglong4* dst = (ulonglong4*)(bits + (long)row * 4);
        ulonglong4 v; v.x = b0; v.y = b1; v.z = b2; v.w = b3;
        *dst = v;
    }
}

// ---------------- K2: g2 from bitmask + exact min-plus column pass ----------
// Block = 256 threads = one slice's 16-col strip (grid 48*16).
// LDS: slice bitmask (8 KB) + column-major g2 tile, stride 273 (odd -> 2-way
// max bank alias on the hot reads, free) with 8 pad rows each side.
__global__ __launch_bounds__(256) void k2_colpass(const unsigned long long* __restrict__ bits,
                                                  float* __restrict__ d2out,
                                                  float* __restrict__ stripmax) {
    __shared__ unsigned long long bm[1024];   // [row*4 + cc]
    __shared__ float tile[16 * 273];          // row r at tile[c*273 + 8 + r]
    __shared__ float wm[4];
    int bx = blockIdx.x;
    int slice = bx >> 4;
    int w0 = (bx & 15) * 16;
    int tid = threadIdx.x;

    // load slice bitmask: 1024 ull, coalesced
    {
        const unsigned long long* src = bits + (long)slice * 1024;
        #pragma unroll
        for (int i = 0; i < 4; ++i) bm[i * 256 + tid] = src[i * 256 + tid];
    }
    // pad rows: tile idx 0..7 (rows -8..-1) and 264..271 (rows 256..263)
    {
        int c = tid >> 4, i = tid & 15;
        tile[c * 273 + (i < 8 ? i : 256 + i)] = PADV;
    }
    __syncthreads();

    int c = tid & 15;                 // column within strip
    int p = w0 + c;                   // global column 0..255
    int rg = tid >> 4;                // 0..15

    // nearest-zero squared distance for (row, col p) from LDS bitmask
    auto nz2 = [&](int row) -> float {
        int dist = 512;               // BIG cap (H+W), matches reference
        #pragma unroll
        for (int cc = 0; cc < 4; ++cc) {
            unsigned long long M = bm[row * 4 + cc];
            int q = p - cc;                          // >= -3
            int qa = (q < 0) ? 0 : q;
            int tp = qa >> 2;                        // floor(q/4) for q>=0
            unsigned long long Ml = (q >= 0) ? (M & (~0ull >> (63 - tp))) : 0ull;
            int tn = (q < 0) ? 0 : ((q + 3) >> 2);   // ceil(q/4)
            unsigned long long Mh = (tn < 64) ? (M & (~0ull << tn)) : 0ull;
            if (Ml) dist = min(dist, q - 4 * (63 - __builtin_clzll(Ml)));
            if (Mh) dist = min(dist, 4 * __builtin_ctzll(Mh) - q);
        }
        float fd = (float)dist;
        return fd * fd;
    };

    // g2 for 16 rows each (strided rows -> small LDS write alias, cheap)
    #pragma unroll
    for (int k = 0; k < 16; ++k) {
        int r = rg + 16 * k;
        tile[c * 273 + 8 + r] = nz2(r);
    }
    __syncthreads();

    // window pass (+-8): contiguous ownership rows r0..r0+15
    int r0 = rg * 16;
    float s[32];                       // rows r0-8 .. r0+23 of column c
    #pragma unroll
    for (int i = 0; i < 32; ++i) s[i] = tile[c * 273 + r0 + i];

    float dmin[16];
    #pragma unroll
    for (int k = 0; k < 16; ++k) dmin[k] = s[k + 8];    // o = 0
    #pragma unroll
    for (int o = -8; o <= 8; ++o) {
        if (o == 0) continue;
        float oo = (float)(o * o);
        #pragma unroll
        for (int k = 0; k < 16; ++k)
            dmin[k] = fminf(dmin[k], s[k + 8 + o] + oo);
    }

    // per-pixel exact fallback: windowed min > 80 can't certify optimality
    // within +-8 (excluded candidates >= 81); rescan full column in LDS.
    // Never taken for random masks -> execz-skipped.
    #pragma unroll
    for (int k = 0; k < 16; ++k) {
        if (dmin[k] > 80.0f) {
            float best = dmin[k];
            int r = r0 + k;
            for (int rp = 0; rp < 256; ++rp) {
                float dr = (float)(r - rp);
                best = fminf(best, fmaf(dr, dr, tile[c * 273 + 8 + rp]));
            }
            dmin[k] = best;
        }
    }

    // write back d2 (L2-resident; K3 consumes immediately), track block max
    float* dst = d2out + (long)slice * 65536 + w0 + c;
    float m = 0.f;
    #pragma unroll
    for (int k = 0; k < 16; ++k) {
        dst[(long)(r0 + k) * 256] = dmin[k];
        m = fmaxf(m, dmin[k]);
    }
    #pragma unroll
    for (int off = 32; off >= 1; off >>= 1)
        m = fmaxf(m, __shfl_down(m, off, 64));
    if ((tid & 63) == 0) wm[tid >> 6] = m;
    __syncthreads();
    if (tid == 0)
        stripmax[bx] = fmaxf(fmaxf(wm[0], wm[1]), fmaxf(wm[2], wm[3]));
}

// ---------------- K3: epilogue ---------------------------------------------
// 64 blocks per slice; each block reduces the slice's 16 strip maxes once.
__global__ __launch_bounds__(256) void k3_final(float* __restrict__ out,
                                                const float* __restrict__ stripmax) {
    __shared__ float sMx;
    int tid = threadIdx.x;
    int idx4 = blockIdx.x * 256 + tid;    // float4 index, 786432 total
    int slice = blockIdx.x >> 6;          // 64 blocks per slice
    if (tid < 16) {
        float v = stripmax[slice * 16 + tid];
        #pragma unroll
        for (int off = 8; off >= 1; off >>= 1) v = fmaxf(v, __shfl_down(v, off, 64));
        if (tid == 0) sMx = v;
    }
    __syncthreads();

    int c = slice % 3;
    float wgt = (c == 0) ? 0.5f : ((c == 1) ? 1.0f : 2.0f);
    float mx = wgt * __builtin_sqrtf(sMx);

    float4 d2 = ((float4*)out)[idx4];
    float4 r;
    if (mx > 0.f) {
        float inv = 1.0f / mx;
        r.x = (mx - wgt * __builtin_sqrtf(d2.x)) * inv;
        r.y = (mx - wgt * __builtin_sqrtf(d2.y)) * inv;
        r.z = (mx - wgt * __builtin_sqrtf(d2.z)) * inv;
        r.w = (mx - wgt * __builtin_sqrtf(d2.w)) * inv;
    } else {
        r.x = wgt * __builtin_sqrtf(d2.x);
        r.y = wgt * __builtin_sqrtf(d2.y);
        r.z = wgt * __builtin_sqrtf(d2.z);
        r.w = wgt * __builtin_sqrtf(d2.w);
    }
    ((float4*)out)[idx4] = r;
}

extern "C" void kernel_launch(void* const* d_in, const int* in_sizes, int n_in,
                              void* d_out, int out_size, void* d_ws, size_t ws_size,
                              hipStream_t stream) {
    const float* in = (const float*)d_in[0];
    float* out = (float*)d_out;
    float* stripmax = (float*)d_ws;                                        // 768 floats
    unsigned long long* bits = (unsigned long long*)((char*)d_ws + 4096);  // 384 KB

    k1_bitmask<<<3072, 256, 0, stream>>>(in, bits);       // 12288 rows, wave/row
    k2_colpass<<<768, 256, 0, stream>>>(bits, out, stripmax);  // d2 in place in out
    k3_final<<<3072, 256, 0, stream>>>(out, stripmax);    // 786432 float4
}